// Round 13
// baseline (50.067 us; speedup 1.0000x reference)
//
#include <hip/hip_runtime.h>

constexpr int DSZ = 192, HSZ = 192, WSZ = 192, BSZ = 2;
constexpr int WQ  = WSZ / 4;            // 48 float4 per row
constexpr int HT  = 12;                 // h-rows per tile
constexpr int NHT = HSZ / HT;           // 16
constexpr int DT  = 12;                 // planes per d-chunk
constexpr int NDC = DSZ / DT;           // 16
constexpr int TPB = 192;
constexpr int NBLOCKS = BSZ * NHT * NDC;   // 512, %8==0
constexpr int PPT = HT * WQ / TPB;      // 3 positions per thread
constexpr int HW  = HSZ * WSZ;
constexpr float SMOOTH = 1e-5f;

__device__ __forceinline__ float4 ld4(const float* __restrict__ p) {
    return *reinterpret_cast<const float4*>(p);
}

__device__ __forceinline__ float fsqrt(float x) {
    return __builtin_amdgcn_sqrtf(x);
}

// barrier that does NOT drain vmcnt: own LDS writes visible (lgkmcnt) + s_barrier.
// Global prefetches stay in flight across steps (register-dep ordered).
__device__ __forceinline__ void wg_barrier() {
    asm volatile("s_waitcnt lgkmcnt(0)" ::: "memory");
    __builtin_amdgcn_s_barrier();
    __builtin_amdgcn_sched_barrier(0);
}

__device__ __forceinline__ void mag4(float4 c, float4 hm, float4 hn,
                                     float4 d0, float4 d1, float wl, float wr,
                                     float o[4]) {
    float gx0 = d1.x - d0.x, gx1 = d1.y - d0.y, gx2 = d1.z - d0.z, gx3 = d1.w - d0.w;
    float gy0 = hn.x - hm.x, gy1 = hn.y - hm.y, gy2 = hn.z - hm.z, gy3 = hn.w - hm.w;
    float gz0 = c.y - wl,    gz1 = c.z - c.x,   gz2 = c.w - c.y,   gz3 = wr - c.z;
    o[0] = fsqrt(fmaf(gx0, gx0, fmaf(gy0, gy0, fmaf(gz0, gz0, SMOOTH))));
    o[1] = fsqrt(fmaf(gx1, gx1, fmaf(gy1, gy1, fmaf(gz1, gz1, SMOOTH))));
    o[2] = fsqrt(fmaf(gx2, gx2, fmaf(gy2, gy2, fmaf(gz2, gz2, SMOOTH))));
    o[3] = fsqrt(fmaf(gx3, gx3, fmaf(gy3, gy3, fmaf(gz3, gz3, SMOOTH))));
}

// w-edges via cross-lane shuffle (wrap lanes are exactly the masked ones)
__device__ __forceinline__ void edges(float4 r, int wq, float& wl, float& wr) {
    float up = __shfl_up(r.w, 1);
    float dn = __shfl_down(r.x, 1);
    wl = (wq > 0)      ? up : 0.f;
    wr = (wq < WQ - 1) ? dn : 0.f;
}

// One pipeline step: issue plane d0+S+3 into GI/HI; compute plane d0+S;
// stage plane d0+S+1; consume GC/HC (plane d0+S+2, issued one step ago).
#define BL_STEP(S, CUR, NXT, GI, GC, HI, HC)                                   \
    {                                                                          \
        const int q   = d0 + (S) + 3;                                          \
        const bool vq = ((S) <= DT - 3) && (q < DSZ);                          \
        _Pragma("unroll")                                                      \
        for (int k = 0; k < PPT; ++k) {                                        \
            const size_t ro = (size_t)(r0 + 4 * k) * WSZ + (size_t)q * HW;     \
            GI[k][0] = vq ? ld4(base0 + ro) : z;                               \
            GI[k][1] = vq ? ld4(base1 + ro) : z;                               \
        }                                                                      \
        HI[0] = (vq && hvalid) ? ld4(hbase0 + (size_t)q * HW) : z;             \
        HI[1] = (vq && hvalid) ? ld4(hbase1 + (size_t)q * HW) : z;             \
        _Pragma("unroll")                                                      \
        for (int k = 0; k < PPT; ++k) {                                        \
            const int r = r0 + 4 * k;                                          \
            float m0[4], m1[4];                                                \
            {                                                                  \
                float4 hm = sbuf[CUR][0][r][wq];                               \
                float4 hn = sbuf[CUR][0][r + 2][wq];                           \
                float wl, wr;                                                  \
                edges(cC[k][0], wq, wl, wr);                                   \
                mag4(cC[k][0], hm, hn, cP[k][0], cN[k][0], wl, wr, m0);        \
            }                                                                  \
            {                                                                  \
                float4 hm = sbuf[CUR][1][r][wq];                               \
                float4 hn = sbuf[CUR][1][r + 2][wq];                           \
                float wl, wr;                                                  \
                edges(cC[k][1], wq, wl, wr);                                   \
                mag4(cC[k][1], hm, hn, cP[k][1], cN[k][1], wl, wr, m1);        \
            }                                                                  \
            _Pragma("unroll")                                                  \
            for (int j = 0; j < 4; ++j) {                                      \
                s_pt = fmaf(m0[j], m1[j], s_pt);                               \
                s_p += m0[j];                                                  \
                s_t += m1[j];                                                  \
            }                                                                  \
        }                                                                      \
        _Pragma("unroll")                                                      \
        for (int k = 0; k < PPT; ++k) {                                        \
            sbuf[NXT][0][r0 + 4 * k + 1][wq] = cN[k][0];                       \
            sbuf[NXT][1][r0 + 4 * k + 1][wq] = cN[k][1];                       \
        }                                                                      \
        if (isHalo) {                                                          \
            sbuf[NXT][0][hrow + 1][hwq] = hNxt[0];                             \
            sbuf[NXT][1][hrow + 1][hwq] = hNxt[1];                             \
        }                                                                      \
        _Pragma("unroll")                                                      \
        for (int k = 0; k < PPT; ++k) {                                        \
            cP[k][0] = cC[k][0]; cC[k][0] = cN[k][0]; cN[k][0] = GC[k][0];     \
            cP[k][1] = cC[k][1]; cC[k][1] = cN[k][1]; cN[k][1] = GC[k][1];     \
        }                                                                      \
        hNxt[0] = HC[0]; hNxt[1] = HC[1];                                      \
        wg_barrier();                                                          \
    }

__global__ __launch_bounds__(TPB)
void bl_main(const float* __restrict__ pred,
             const float* __restrict__ target,
             double* __restrict__ acc) {
    // LDS: 2 buffers x 2 arrays x (HT+2) rows x 48 float4 = 43 KB
    __shared__ float4 sbuf[2][2][HT + 2][WQ];

    const int bid = (int)blockIdx.x;
    const int swz = (bid & 7) * (NBLOCKS / 8) + (bid >> 3);  // XCD-chunked
    int t = swz;
    const int dc = t % NDC; t /= NDC;
    const int ht = t % NHT; t /= NHT;
    const int b  = t;
    const int d0 = dc * DT;
    const int h0 = ht * HT;

    const int tid = threadIdx.x;
    const int wq  = tid % WQ;
    const int r0  = tid / WQ;          // 0..3; rows handled: r0+4k

    const float4 z = make_float4(0.f, 0.f, 0.f, 0.f);
    const float* __restrict__ base0 = pred   + (size_t)b * DSZ * HW + (size_t)h0 * WSZ + wq * 4;
    const float* __restrict__ base1 = target + (size_t)b * DSZ * HW + (size_t)h0 * WSZ + wq * 4;

    // halo roles: threads 0..47 -> row -1, threads 48..95 -> row HT
    const bool isHalo = (tid < 2 * WQ);
    const int  hrow   = (tid < WQ) ? -1 : HT;
    const int  hwq    = (tid < WQ) ? tid : tid - WQ;
    const bool hvalid = isHalo && (h0 + hrow >= 0) && (h0 + hrow < HSZ);
    const float* __restrict__ hbase0 =
        pred   + (size_t)b * DSZ * HW + (size_t)(h0 + hrow) * WSZ + hwq * 4;
    const float* __restrict__ hbase1 =
        target + (size_t)b * DSZ * HW + (size_t)(h0 + hrow) * WSZ + hwq * 4;

    float4 cP[PPT][2], cC[PPT][2], cN[PPT][2];
    float4 fA[PPT][2], fB[PPT][2];          // ping-pong in-flight plane buffers
    float4 hNxt[2], hA[2], hB[2];

    // ---- prologue: own rows at planes d0-1, d0, d0+1; in-flight fA = d0+2
    #pragma unroll
    for (int k = 0; k < PPT; ++k) {
        const size_t ro = (size_t)(r0 + 4 * k) * WSZ;
        #pragma unroll
        for (int a = 0; a < 2; ++a) {
            const float* bb = a ? base1 : base0;
            cP[k][a] = (d0 > 0) ? ld4(bb + ro + (size_t)(d0 - 1) * HW) : z;
            cC[k][a] = ld4(bb + ro + (size_t)d0 * HW);
            cN[k][a] = ld4(bb + ro + (size_t)(d0 + 1) * HW);   // d0+1 <= 181
            fA[k][a] = ld4(bb + ro + (size_t)(d0 + 2) * HW);   // d0+2 <= 182
        }
    }
    float4 hCur[2];
    #pragma unroll
    for (int a = 0; a < 2; ++a) {
        const float* hb = a ? hbase1 : hbase0;
        hCur[a] = hvalid ? ld4(hb + (size_t)d0 * HW)       : z;
        hNxt[a] = hvalid ? ld4(hb + (size_t)(d0 + 1) * HW) : z;
        hA[a]   = hvalid ? ld4(hb + (size_t)(d0 + 2) * HW) : z;
    }
    // stage plane d0 into buffer 0
    #pragma unroll
    for (int k = 0; k < PPT; ++k)
        #pragma unroll
        for (int a = 0; a < 2; ++a)
            sbuf[0][a][r0 + 4 * k + 1][wq] = cC[k][a];
    if (isHalo) {
        #pragma unroll
        for (int a = 0; a < 2; ++a)
            sbuf[0][a][hrow + 1][hwq] = hCur[a];
    }
    wg_barrier();

    float s_pt = 0.f, s_p = 0.f, s_t = 0.f;

    // ---- main d-march, 2-phase software pipeline (issue->consume = 1 full step)
    #pragma unroll 1
    for (int u = 0; u < DT / 2; ++u) {
        const int s0 = 2 * u;
        BL_STEP(s0,     0, 1, fB, fA, hB, hA)
        BL_STEP(s0 + 1, 1, 0, fA, fB, hA, hB)
    }

    // ---- reduction (3 waves)
    #pragma unroll
    for (int off = 32; off; off >>= 1) {
        s_pt += __shfl_down(s_pt, off);
        s_p  += __shfl_down(s_p,  off);
        s_t  += __shfl_down(s_t,  off);
    }

    __shared__ float red[3][4];
    const int lane = tid & 63;
    const int wid  = tid >> 6;
    if (lane == 0) {
        red[wid][0] = s_pt;
        red[wid][1] = s_p;
        red[wid][2] = s_t;
    }
    __syncthreads();
    if (tid == 0) {
        double a_pt = 0.0, a_p = 0.0, a_t = 0.0;
        #pragma unroll
        for (int k = 0; k < 3; ++k) {
            a_pt += (double)red[k][0];
            a_p  += (double)red[k][1];
            a_t  += (double)red[k][2];
        }
        atomicAdd(&acc[0],  a_pt);
        atomicAdd(&acc[8],  a_p);
        atomicAdd(&acc[16], a_t);
    }
}

__global__ void bl_final(const double* __restrict__ acc, float* __restrict__ out) {
    const double I = acc[0];
    const double Pm = acc[8];
    const double Tm = acc[16];
    const double dice = (2.0 * I + 1e-5) / (Pm + Tm + 1e-5);
    out[0] = (float)(1.0 - dice);
}

extern "C" void kernel_launch(void* const* d_in, const int* in_sizes, int n_in,
                              void* d_out, int out_size, void* d_ws, size_t ws_size,
                              hipStream_t stream) {
    const float* pred   = (const float*)d_in[0];
    const float* target = (const float*)d_in[1];
    double* acc = (double*)d_ws;

    (void)hipMemsetAsync(d_ws, 0, 17 * sizeof(double), stream);
    bl_main<<<NBLOCKS, TPB, 0, stream>>>(pred, target, acc);
    bl_final<<<1, 1, 0, stream>>>(acc, (float*)d_out);
}

// Round 14
// 41.690 us; speedup vs baseline: 1.2010x; 1.2010x over previous
//
#include <hip/hip_runtime.h>

constexpr int DSZ = 192, HSZ = 192, WSZ = 192;
constexpr int WQ   = WSZ / 4;          // 48 float4 per row
constexpr int RB   = 4;                // h-rows per block
constexpr int TPB  = RB * WQ;          // 192 threads (3 waves)
constexpr int SLAB = 48;               // planes per XCD slab (8 slabs = 2 batches x 192)
constexpr int CH   = 24;               // planes marched per thread
constexpr int NCHUNK = SLAB / CH;      // 2
constexpr int NBAND  = HSZ / RB;       // 48
constexpr int NBLOCKS = 8 * NCHUNK * NBAND;  // 768 = 3 blocks/CU, all resident
constexpr int HW = HSZ * WSZ;
constexpr float SMOOTH = 1e-5f;

__device__ __forceinline__ float4 ld4(const float* __restrict__ p) {
    return *reinterpret_cast<const float4*>(p);
}

__device__ __forceinline__ float fsqrt(float x) {
    return __builtin_amdgcn_sqrtf(x);   // raw v_sqrt_f32
}

__device__ __forceinline__ void mag4(float4 c, float4 hm, float4 hn,
                                     float4 d0, float4 d1, float wl, float wr,
                                     float o[4]) {
    float gx0 = d1.x - d0.x, gx1 = d1.y - d0.y, gx2 = d1.z - d0.z, gx3 = d1.w - d0.w;
    float gy0 = hn.x - hm.x, gy1 = hn.y - hm.y, gy2 = hn.z - hm.z, gy3 = hn.w - hm.w;
    float gz0 = c.y - wl,    gz1 = c.z - c.x,   gz2 = c.w - c.y,   gz3 = wr - c.z;
    o[0] = fsqrt(fmaf(gx0, gx0, fmaf(gy0, gy0, fmaf(gz0, gz0, SMOOTH))));
    o[1] = fsqrt(fmaf(gx1, gx1, fmaf(gy1, gy1, fmaf(gz1, gz1, SMOOTH))));
    o[2] = fsqrt(fmaf(gx2, gx2, fmaf(gy2, gy2, fmaf(gz2, gz2, SMOOTH))));
    o[3] = fsqrt(fmaf(gx3, gx3, fmaf(gy3, gy3, fmaf(gz3, gz3, SMOOTH))));
}

// w-edges via cross-lane shuffle (lanes map 1:1 to consecutive wq within a row)
__device__ __forceinline__ void edges(float4 r, int wq, float& wl, float& wr) {
    float up = __shfl_up(r.w, 1);
    float dn = __shfl_down(r.x, 1);
    wl = (wq > 0)      ? up : 0.f;
    wr = (wq < WQ - 1) ? dn : 0.f;
}

__global__ __launch_bounds__(TPB)
void bl_main(const float* __restrict__ pred,
             const float* __restrict__ target,
             double* __restrict__ acc) {
    // XCD-cooperative decomposition: bid&7 -> XCD slab of 48 planes.
    // All 96 blocks of an XCD cover full HxW of the same planes and march d
    // together -> h-halo re-reads hit the XCD's 4MB L2 (live set ~2.4MB).
    const int bid  = (int)blockIdx.x;
    const int slab = bid & 7;            // 0..7 -> (batch, d-slab)
    const int idx  = bid >> 3;           // 0..95
    const int chunk = idx % NCHUNK;      // 2 d-fronts per XCD
    const int band  = idx / NCHUNK;      // 0..47 h-band

    const int b      = slab >> 2;                          // batch
    const int dstart = (slab & 3) * SLAB + chunk * CH;     // within-batch d base

    const int tid = threadIdx.x;
    const int wq  = tid % WQ;
    const int h   = band * RB + tid / WQ;

    const float4 z = make_float4(0.f, 0.f, 0.f, 0.f);
    const float* __restrict__ P = pred   + (size_t)b * DSZ * HW + (size_t)h * WSZ + wq * 4;
    const float* __restrict__ T = target + (size_t)b * DSZ * HW + (size_t)h * WSZ + wq * 4;

    // rolling 2-plane window (d-1, d); d-1 of warmup is interior unless dstart==0
    float4 pm, pc, tm, tc;
    pc = ld4(P + (size_t)dstart * HW);
    tc = ld4(T + (size_t)dstart * HW);
    if (dstart > 0) {
        pm = ld4(P + (size_t)(dstart - 1) * HW);
        tm = ld4(T + (size_t)(dstart - 1) * HW);
    } else {
        pm = z; tm = z;
    }

    float s_pt = 0.f, s_p = 0.f, s_t = 0.f;

    #pragma unroll 1
    for (int s = 0; s < CH; ++s) {
        const int d = dstart + s;
        const size_t dOff = (size_t)d * HW;

        float4 pn  = (d < DSZ - 1) ? ld4(P + dOff + HW)  : z;
        float4 tn  = (d < DSZ - 1) ? ld4(T + dOff + HW)  : z;
        float4 phm = (h > 0)       ? ld4(P + dOff - WSZ) : z;
        float4 thm = (h > 0)       ? ld4(T + dOff - WSZ) : z;
        float4 phn = (h < HSZ - 1) ? ld4(P + dOff + WSZ) : z;
        float4 thn = (h < HSZ - 1) ? ld4(T + dOff + WSZ) : z;

        float wl, wr;
        float pb[4], tb[4];
        edges(pc, wq, wl, wr);
        mag4(pc, phm, phn, pm, pn, wl, wr, pb);
        edges(tc, wq, wl, wr);
        mag4(tc, thm, thn, tm, tn, wl, wr, tb);

        #pragma unroll
        for (int j = 0; j < 4; ++j) {
            s_pt = fmaf(pb[j], tb[j], s_pt);
            s_p += pb[j];
            s_t += tb[j];
        }

        pm = pc; pc = pn;
        tm = tc; tc = tn;
    }

    // 64-lane wave reduction
    #pragma unroll
    for (int off = 32; off; off >>= 1) {
        s_pt += __shfl_down(s_pt, off);
        s_p  += __shfl_down(s_p,  off);
        s_t  += __shfl_down(s_t,  off);
    }

    __shared__ float red[3][4];   // 3 waves x {pt,p,t}
    const int lane = tid & 63;
    const int wid  = tid >> 6;
    if (lane == 0) {
        red[wid][0] = s_pt;
        red[wid][1] = s_p;
        red[wid][2] = s_t;
    }
    __syncthreads();
    if (tid == 0) {
        double a_pt = 0.0, a_p = 0.0, a_t = 0.0;
        #pragma unroll
        for (int k = 0; k < 3; ++k) {
            a_pt += (double)red[k][0];
            a_p  += (double)red[k][1];
            a_t  += (double)red[k][2];
        }
        atomicAdd(&acc[0],  a_pt);
        atomicAdd(&acc[8],  a_p);
        atomicAdd(&acc[16], a_t);
    }
}

__global__ void bl_final(const double* __restrict__ acc, float* __restrict__ out) {
    const double I = acc[0];
    const double Pm = acc[8];
    const double Tm = acc[16];
    const double dice = (2.0 * I + 1e-5) / (Pm + Tm + 1e-5);
    out[0] = (float)(1.0 - dice);
}

extern "C" void kernel_launch(void* const* d_in, const int* in_sizes, int n_in,
                              void* d_out, int out_size, void* d_ws, size_t ws_size,
                              hipStream_t stream) {
    const float* pred   = (const float*)d_in[0];
    const float* target = (const float*)d_in[1];
    double* acc = (double*)d_ws;

    (void)hipMemsetAsync(d_ws, 0, 17 * sizeof(double), stream);
    bl_main<<<NBLOCKS, TPB, 0, stream>>>(pred, target, acc);
    bl_final<<<1, 1, 0, stream>>>(acc, (float*)d_out);
}